// Round 7
// baseline (316.315 us; speedup 1.0000x reference)
//
#include <hip/hip_runtime.h>
#include <math.h>

#define NH   16
#define DK   64
#define SEQL 1024
#define NB   8
#define DIN  1024
#define PSTR 76   // P-buffer row stride (elems): word-stride 38 == 6 mod 32 ->
                  // 16 lanes hit 16 distinct even banks (72 gave 4-8-way)

typedef __bf16 bf16;
typedef __attribute__((ext_vector_type(8))) __bf16 bf16x8;
typedef __attribute__((ext_vector_type(4))) __bf16 bf16x4;
typedef __attribute__((ext_vector_type(4))) float f32x4;

// fold 1/sqrt(d_k)=1/8 and log2(e) into Q so softmax uses exp2
#define QSCALE 0.18033688011112042f

static __device__ __forceinline__ f32x4 mfma_bf16(bf16x8 a, bf16x8 b, f32x4 c) {
  return __builtin_amdgcn_mfma_f32_16x16x32_bf16(a, b, c, 0, 0, 0);
}

// async global->LDS, 16B per lane. LDS dest = wave-uniform base + lane*16.
static __device__ __forceinline__ void async16(const void* g, void* l) {
  __builtin_amdgcn_global_load_lds(
      (const __attribute__((address_space(1))) void*)g,
      (__attribute__((address_space(3))) void*)l, 16, 0, 0);
}

// ---------------------------------------------------------------------------
// fp32 -> bf16, 3 tensors per dispatch (blockIdx.y selects), 8 elems/thread.
// NOW ONLY USED FOR WEIGHTS (q/k/v conversion is folded into proj staging).
// ---------------------------------------------------------------------------
__global__ __launch_bounds__(256)
void cvt3_kernel(const float* __restrict__ s0, const float* __restrict__ s1,
                 const float* __restrict__ s2, bf16* __restrict__ d0,
                 bf16* __restrict__ d1, bf16* __restrict__ d2, int n8) {
  const int i = blockIdx.x * 256 + threadIdx.x;
  if (i >= n8) return;
  const float* s = (blockIdx.y == 0) ? s0 : (blockIdx.y == 1) ? s1 : s2;
  bf16*        d = (blockIdx.y == 0) ? d0 : (blockIdx.y == 1) ? d1 : d2;
  const f32x4* sp = (const f32x4*)s;
  const f32x4 a = sp[2 * i], b = sp[2 * i + 1];
  bf16x8 r;
  r[0] = (bf16)a[0]; r[1] = (bf16)a[1]; r[2] = (bf16)a[2]; r[3] = (bf16)a[3];
  r[4] = (bf16)b[0]; r[5] = (bf16)b[1]; r[6] = (bf16)b[2]; r[7] = (bf16)b[3];
  ((bf16x8*)d)[i] = r;
}

// ---------------------------------------------------------------------------
// QKV projection GEMM, one dispatch (z selects Q/K/V): Y = X.W^T + b
// M = nb*1024, N = 1024, K = 1024. m97-style global_load_lds staging,
// 128x128 tile, BK=32, 4 waves. (256^2 8-phase LOST here in R1/R2.)
//
// X (q/k/v input) is consumed DIRECTLY AS FP32: staged to a 16 KB fp32 LDS
// tile (rows 128 B, 16B-chunk XOR swizzle phys = chunk ^ (row&7) via
// pre-swizzled global source) and converted to bf16 at fragment build
// (2x f32x4 ds_read + scalar casts -> compiler cvt_pk; same RNE rounding as
// the old cvt kernel -> bit-identical). This kills the 151 MB q/k/v
// pre-convert pass entirely. W stays bf16 (tiny, still pre-converted).
//
// Operand orientation per z (packed 8B stores both ways):
//   z<2 (Q,K out [bl,h,s,d]): A = W rows, B = X rows -> acc reg axis = d.
//   z==2 (V out TRANSPOSED [bl,h,d,s]): A = X rows, B = W rows -> reg = s.
// ---------------------------------------------------------------------------
__global__ __launch_bounds__(256, 2)
void proj_kernel(const float* __restrict__ Xq, const float* __restrict__ Xk,
                 const float* __restrict__ Xv,
                 const bf16* __restrict__ Wq, const bf16* __restrict__ Wk,
                 const bf16* __restrict__ Wv,
                 const float* __restrict__ Bq, const float* __restrict__ Bk,
                 const float* __restrict__ Bv,
                 bf16* __restrict__ Yq, bf16* __restrict__ Yk,
                 bf16* __restrict__ Yv) {
  const int z = blockIdx.z;
  const float* X  = (z == 0) ? Xq : (z == 1) ? Xk : Xv;
  const bf16*  W  = (z == 0) ? Wq : (z == 1) ? Wk : Wv;
  const float* Bi = (z == 0) ? Bq : (z == 1) ? Bk : Bv;
  bf16*        Y  = (z == 0) ? Yq : (z == 1) ? Yk : Yv;

  const int m0 = blockIdx.x * 128;
  const int n0 = blockIdx.y * 128;

  // X: 128 rows x 32 fp32 (128B rows, 8x16B chunks, phys = log ^ (row&7))
  __shared__ __attribute__((aligned(16))) float Xs[128 * 32];  // 16 KB
  // W: 128 rows x 32 bf16 (64B rows, 4x16B chunks, phys = log ^ ((row>>1)&3))
  __shared__ __attribute__((aligned(16))) bf16  Ws[128 * 32];  // 8 KB

  const int t    = threadIdx.x;
  const int l    = t & 63;
  const int w    = t >> 6;
  const int l15  = l & 15;
  const int quad = l >> 4;
  const int wm   = w & 1;   // X-row half (both orientations)
  const int wn   = w >> 1;  // W-row half

  f32x4 acc[4][4];
#pragma unroll
  for (int i = 0; i < 4; ++i)
#pragma unroll
    for (int j = 0; j < 4; ++j) acc[i][j] = (f32x4){0.f, 0.f, 0.f, 0.f};

  // W staging (unchanged): 16-row slabs, 4 lanes/row
  const int srow   = l >> 2;
  const int gchunk = (l & 3) ^ ((l >> 3) & 3);
  // X staging: 8-row slabs, 8 lanes/row, pre-swizzled global chunk
  const int xrow   = l >> 3;
  const int xchunk = (l & 7) ^ xrow;   // 16B chunk = 4 fp32

  const int rx7 = l15 & 7;

  for (int k0 = 0; k0 < DIN; k0 += 32) {
    __syncthreads();
#pragma unroll
    for (int i = 0; i < 2; ++i) {
      const int slab = w * 32 + i * 16;
      const int r    = slab + srow;
      async16(W + (size_t)(n0 + r) * DIN + k0 + gchunk * 8, Ws + slab * 32);
    }
#pragma unroll
    for (int c = 0; c < 4; ++c) {
      const int slab = w * 32 + c * 8;
      const int r    = slab + xrow;
      async16(X + (size_t)(m0 + r) * DIN + k0 + xchunk * 4, Xs + slab * 32);
    }
    __syncthreads();  // vmcnt(0) drain before s_barrier

    bf16x8 xf[4], wf[4];
    const int swzW = quad ^ ((l15 >> 1) & 3);
#pragma unroll
    for (int i = 0; i < 4; ++i) {
      const int xr = wm * 64 + i * 16 + l15;
      const f32x4 lo = *(const f32x4*)(Xs + xr * 32 + (((quad << 1) | 0) ^ rx7) * 4);
      const f32x4 hi = *(const f32x4*)(Xs + xr * 32 + (((quad << 1) | 1) ^ rx7) * 4);
#pragma unroll
      for (int j = 0; j < 4; ++j) {
        xf[i][j]     = (bf16)lo[j];
        xf[i][4 + j] = (bf16)hi[j];
      }
      wf[i] = *(const bf16x8*)(Ws + (wn * 64 + i * 16 + l15) * 32 + swzW * 8);
    }
    if (z == 2) {
#pragma unroll
      for (int mi = 0; mi < 4; ++mi)
#pragma unroll
        for (int nj = 0; nj < 4; ++nj)
          acc[mi][nj] = mfma_bf16(xf[mi], wf[nj], acc[mi][nj]);
    } else {
#pragma unroll
      for (int mi = 0; mi < 4; ++mi)
#pragma unroll
        for (int nj = 0; nj < 4; ++nj)
          acc[mi][nj] = mfma_bf16(wf[mi], xf[nj], acc[mi][nj]);
    }
  }

  // acc[mi][nj]: reg rows (quad*4+r) <-> A-operand rows, cols (l15) <-> B rows
  if (z == 2) {
    // V: transposed [bl, h, d, s] — r maps to 4 consecutive s -> 8B store
#pragma unroll
    for (int nj = 0; nj < 4; ++nj) {
      const int o    = n0 + wn * 64 + nj * 16 + l15;
      const float bv = Bi[o];
      const int h    = o >> 6;
      const int d    = o & 63;
#pragma unroll
      for (int mi = 0; mi < 4; ++mi) {
        const int m  = m0 + wm * 64 + mi * 16 + quad * 4;
        const int bl = m >> 10;
        const int s  = m & (SEQL - 1);
        bf16x4 pk;
#pragma unroll
        for (int r = 0; r < 4; ++r) pk[r] = (bf16)(acc[mi][nj][r] + bv);
        *(bf16x4*)(Y + ((size_t)(bl * NH + h) * DK + d) * SEQL + s) = pk;
      }
    }
  } else {
    // Q/K: [bl,h,s,d] — r maps to 4 consecutive d -> 8B store
    const float scale = (z == 0) ? QSCALE : 1.0f;
    const int hq = (n0 + wn * 64) >> 6;  // head index, constant per wave
#pragma unroll
    for (int mi = 0; mi < 4; ++mi) {
      const int dbase = mi * 16 + quad * 4;
      const f32x4 bv4 = *(const f32x4*)(Bi + n0 + wn * 64 + dbase);
#pragma unroll
      for (int nj = 0; nj < 4; ++nj) {
        const int m  = m0 + wm * 64 + nj * 16 + l15;
        const int bl = m >> 10;
        const int s  = m & (SEQL - 1);
        bf16x4 pk;
#pragma unroll
        for (int r = 0; r < 4; ++r)
          pk[r] = (bf16)((acc[mi][nj][r] + bv4[r]) * scale);
        *(bf16x4*)(Y + (size_t)(((bl * NH + hq) << 10) | s) * DK + dbase) = pk;
      }
    }
  }
}

// ---------------------------------------------------------------------------
// Attention (r5 structure — measured best, ~67 us): BK=64, block = (local bh,
// 256 q-rows), 4 waves, 64 q/wave (4 groups). KV double-buffered in LDS with
// counted vmcnt: fragments pulled to regs up front, lgkmcnt(0)+barrier frees
// the buffer, tile tt+2 staged into it, compute runs while loads fly;
// vmcnt(4) at tile end (never 0 in steady state). P stride 76 conflict-free.
// Computes S^T = K.Q^T so each lane holds 4 consecutive keys -> packed b64
// P-writes; P is wave-private (intra-wave LDS ordering, no barrier).
// Exact softmax via exp2 (scale folded into Q); denominator via
// MFMA-with-ones on the rounded P (numerator-consistent).
// [r6 32-q/wave occupancy rebuild REGRESSED: VALUBusy 25->58%, per-wave
//  overhead amortizes over half the work. Do not revisit.]
// ---------------------------------------------------------------------------
__global__ __launch_bounds__(256, 2)
void attn_kernel(const bf16* __restrict__ Q, const bf16* __restrict__ K,
                 const bf16* __restrict__ V, float* __restrict__ Out, int b0) {
  const int bhl = blockIdx.x;        // same-bh blocks share K/V (XCD locality)
  const int q0  = blockIdx.y * 256;
  const int bg  = b0 + (bhl >> 4);
  const int h   = bhl & 15;
  const int t    = threadIdx.x;
  const int l    = t & 63;
  const int w    = t >> 6;
  const int l15  = l & 15;
  const int quad = l >> 4;

  const bf16* Qh = Q + (size_t)bhl * SEQL * DK;
  const bf16* Kh = K + (size_t)bhl * SEQL * DK;
  const bf16* Vh = V + (size_t)bhl * DK * SEQL;  // [d][s]

  __shared__ __attribute__((aligned(16))) bf16 sKs[2][64 * 64];      // 16 KB
  __shared__ __attribute__((aligned(16))) bf16 sVt[2][64 * 64];      // 16 KB
  __shared__ __attribute__((aligned(16))) bf16 sPl[4][4][16 * PSTR]; // 38 KB

  // Q fragments (pre-scaled): lane holds Q[q=l15][d=quad*8+j], 2 d-halves
  bf16x8 qf[4][2];
#pragma unroll
  for (int g = 0; g < 4; ++g)
#pragma unroll
    for (int hh = 0; hh < 2; ++hh)
      qf[g][hh] = *(const bf16x8*)(Qh + (size_t)(q0 + w * 64 + g * 16 + l15) * DK +
                                   hh * 32 + quad * 8);

  bf16x8 ones;
#pragma unroll
  for (int j = 0; j < 8; ++j) ones[j] = (bf16)1.0f;

  f32x4 oacc[4][4];
#pragma unroll
  for (int g = 0; g < 4; ++g)
#pragma unroll
    for (int n = 0; n < 4; ++n) oacc[g][n] = (f32x4){0.f, 0.f, 0.f, 0.f};
  f32x4 sacc[4];
#pragma unroll
  for (int g = 0; g < 4; ++g) sacc[g] = (f32x4){0.f, 0.f, 0.f, 0.f};

  const int drow   = l >> 3;  // DMA: row within 8-row sub-slab
  const int dchunk = l & 7;   // DMA: physical 16B chunk

#define STAGE_KV(T, BB)                                                      \
  {                                                                          \
    const int kbs = (T) * 64;                                                \
    _Pragma("unroll")                                                        \
    for (int i = 0; i < 2; ++i) {                                            \
      const int r = w * 16 + i * 8 + drow;                                   \
      async16(Kh + (size_t)(kbs + r) * DK + (dchunk ^ (r & 7)) * 8,          \
              &sKs[BB][(w * 16 + i * 8) * 64]);                              \
      async16(Vh + (size_t)r * SEQL + kbs + (dchunk ^ (r & 7)) * 8,          \
              &sVt[BB][(w * 16 + i * 8) * 64]);                              \
    }                                                                        \
  }

  const int NT = SEQL / 64;  // 16

  // prologue: stage tiles 0 and 1; wait tile 0 (tile 1 stays in flight)
  STAGE_KV(0, 0)
  STAGE_KV(1, 1)
  asm volatile("s_waitcnt vmcnt(4)" ::: "memory");
  __builtin_amdgcn_s_barrier();

  for (int tt = 0; tt < NT; ++tt) {
    const int bb = tt & 1;

    // K fragments: A-operand K[key=c*16+l15][d=hh*32+quad*8+j]
    bf16x8 kf[4][2];
#pragma unroll
    for (int c = 0; c < 4; ++c)
#pragma unroll
      for (int hh = 0; hh < 2; ++hh)
        kf[c][hh] = *(const bf16x8*)(&sKs[bb][(c * 16 + l15) * 64 +
                                     (((hh * 4 + quad) ^ (l15 & 7)) * 8)]);
    // V^T fragments: B-operand V^T[d=n*16+l15][k=hh*32+quad*8+j]
    bf16x8 vfr[4][2];
#pragma unroll
    for (int n = 0; n < 4; ++n)
#pragma unroll
      for (int hh = 0; hh < 2; ++hh)
        vfr[n][hh] = *(const bf16x8*)(&sVt[bb][(n * 16 + l15) * 64 +
                                      (((hh * 4 + quad) ^ (l15 & 7)) * 8)]);

    asm volatile("s_waitcnt lgkmcnt(0)" ::: "memory");
    __builtin_amdgcn_sched_barrier(0);  // rule #18: pin reg-MFMAs below wait
    __builtin_amdgcn_s_barrier();       // all waves hold K/V in regs -> buf free
    if (tt + 2 < NT) STAGE_KV(tt + 2, bb)
    __builtin_amdgcn_sched_barrier(0);

    // S^T = K.Q^T -> exp2 -> packed b64 P-writes (P stored [q][key], str 76)
#pragma unroll
    for (int g = 0; g < 4; ++g) {
#pragma unroll
      for (int c = 0; c < 4; ++c) {
        f32x4 cs = (f32x4){0.f, 0.f, 0.f, 0.f};
        cs = mfma_bf16(kf[c][0], qf[g][0], cs);
        cs = mfma_bf16(kf[c][1], qf[g][1], cs);
        bf16x4 pk;
#pragma unroll
        for (int r = 0; r < 4; ++r) pk[r] = (bf16)exp2f(cs[r]);
        // lane (quad,l15) holds P[q=l15][keys c*16+quad*4 .. +3]
        *(bf16x4*)(&sPl[w][g][l15 * PSTR + c * 16 + quad * 4]) = pk;
      }
    }
    // no barrier: sPl[w] is wave-private; lgkmcnt orders write->read

#pragma unroll
    for (int g = 0; g < 4; ++g) {
      const bf16x8 pf0 = *(const bf16x8*)(&sPl[w][g][l15 * PSTR + quad * 8]);
      const bf16x8 pf1 = *(const bf16x8*)(&sPl[w][g][l15 * PSTR + 32 + quad * 8]);
#pragma unroll
      for (int n = 0; n < 4; ++n) {
        oacc[g][n] = mfma_bf16(pf0, vfr[n][0], oacc[g][n]);
        oacc[g][n] = mfma_bf16(pf1, vfr[n][1], oacc[g][n]);
      }
      sacc[g] = mfma_bf16(pf0, ones, sacc[g]);
      sacc[g] = mfma_bf16(pf1, ones, sacc[g]);
    }

    // counted drain: tile tt+1 landed for all waves; tt+2 stays in flight
    if (tt + 2 < NT) {
      asm volatile("s_waitcnt vmcnt(4)" ::: "memory");
    } else if (tt + 2 == NT) {
      asm volatile("s_waitcnt vmcnt(0)" ::: "memory");
    }
    if (tt + 1 < NT) __builtin_amdgcn_s_barrier();
  }
#undef STAGE_KV

  // epilogue: divide by denominator, write fp32 [b, s, h, d]
#pragma unroll
  for (int g = 0; g < 4; ++g) {
    float linv[4];
#pragma unroll
    for (int r = 0; r < 4; ++r) linv[r] = 1.0f / sacc[g][r];
#pragma unroll
    for (int n = 0; n < 4; ++n) {
      const int d = n * 16 + l15;
#pragma unroll
      for (int r = 0; r < 4; ++r) {
        const int qrow = q0 + w * 64 + g * 16 + quad * 4 + r;
        Out[(size_t)((bg * SEQL + qrow) * NH + h) * DK + d] =
            oacc[g][n][r] * linv[r];
      }
    }
  }
}

extern "C" void kernel_launch(void* const* d_in, const int* in_sizes, int n_in,
                              void* d_out, int out_size, void* d_ws,
                              size_t ws_size, hipStream_t stream) {
  const float* q  = (const float*)d_in[0];
  const float* k  = (const float*)d_in[1];
  const float* v  = (const float*)d_in[2];
  const float* Wq = (const float*)d_in[3];
  const float* bq = (const float*)d_in[4];
  const float* Wk = (const float*)d_in[5];
  const float* bk = (const float*)d_in[6];
  const float* Wv = (const float*)d_in[7];
  const float* bv = (const float*)d_in[8];
  float* out = (float*)d_out;

  // ws layout: [Wq,Wk,Wv bf16: 6MB][Yq,Yk,Yv group] (no X buffers anymore —
  // proj consumes fp32 q/k/v directly)
  const size_t wElems = (size_t)DIN * DIN;
  const size_t wBytes = 3 * wElems * sizeof(bf16);
  const size_t perBatch = 3 * (size_t)SEQL * DIN * sizeof(bf16);  // 6 MB
  int nbg = (ws_size > wBytes) ? (int)((ws_size - wBytes) / perBatch) : 1;
  if (nbg < 1) nbg = 1;
  if (nbg > NB) nbg = NB;

  bf16* Wqb = (bf16*)d_ws;
  bf16* Wkb = Wqb + wElems;
  bf16* Wvb = Wkb + wElems;
  const size_t g1 = (size_t)nbg * SEQL * DIN;
  bf16* Yqb = Wvb + wElems;
  bf16* Ykb = Yqb + g1;
  bf16* Yvb = Ykb + g1;

  const int w8 = (int)(wElems / 8);
  dim3 gW((w8 + 255) / 256, 3);
  cvt3_kernel<<<gW, 256, 0, stream>>>(Wq, Wk, Wv, Wqb, Wkb, Wvb, w8);

  for (int b0 = 0; b0 < NB; b0 += nbg) {
    const int nb = (NB - b0 < nbg) ? (NB - b0) : nbg;
    const size_t xoff = (size_t)b0 * SEQL * DIN;

    dim3 gP(nb * 8, 8, 3);
    proj_kernel<<<gP, 256, 0, stream>>>(q + xoff, k + xoff, v + xoff,
                                        Wqb, Wkb, Wvb,
                                        bq, bk, bv, Yqb, Ykb, Yvb);

    dim3 gA(nb * NH, SEQL / 256);
    attn_kernel<<<gA, 256, 0, stream>>>(Yqb, Ykb, Yvb, out, b0);
  }
}

// Round 8
// 276.433 us; speedup vs baseline: 1.1443x; 1.1443x over previous
//
#include <hip/hip_runtime.h>
#include <math.h>

#define NH   16
#define DK   64
#define SEQL 1024
#define NB   8
#define DIN  1024
#define PSTR 76   // P-buffer row stride (elems): word-stride 38 == 6 mod 32 ->
                  // 16 lanes hit 16 distinct even banks (72 gave 4-8-way)

typedef __bf16 bf16;
typedef __attribute__((ext_vector_type(8))) __bf16 bf16x8;
typedef __attribute__((ext_vector_type(4))) __bf16 bf16x4;
typedef __attribute__((ext_vector_type(4))) float f32x4;

// fold 1/sqrt(d_k)=1/8 and log2(e) into Q so softmax uses exp2
#define QSCALE 0.18033688011112042f

static __device__ __forceinline__ f32x4 mfma_bf16(bf16x8 a, bf16x8 b, f32x4 c) {
  return __builtin_amdgcn_mfma_f32_16x16x32_bf16(a, b, c, 0, 0, 0);
}

// async global->LDS, 16B per lane. LDS dest = wave-uniform base + lane*16.
static __device__ __forceinline__ void async16(const void* g, void* l) {
  __builtin_amdgcn_global_load_lds(
      (const __attribute__((address_space(1))) void*)g,
      (__attribute__((address_space(3))) void*)l, 16, 0, 0);
}

// ---------------------------------------------------------------------------
// fp32 -> bf16, 6 tensors per dispatch (blockIdx.y selects: 0-2 inputs with
// count n8a, 3-5 weights with count n8b), 8 elems/thread.
// [r7 tried folding q/k/v cvt into proj's staging: proj 77->152 us (fp32 LDS
//  tile = 6.3M bank conflicts + 2x fetch + inner-loop casts). Do not revisit.]
// ---------------------------------------------------------------------------
__global__ __launch_bounds__(256)
void cvt6_kernel(const float* __restrict__ s0, const float* __restrict__ s1,
                 const float* __restrict__ s2, const float* __restrict__ s3,
                 const float* __restrict__ s4, const float* __restrict__ s5,
                 bf16* __restrict__ d0, bf16* __restrict__ d1,
                 bf16* __restrict__ d2, bf16* __restrict__ d3,
                 bf16* __restrict__ d4, bf16* __restrict__ d5,
                 int n8a, int n8b) {
  const int y = blockIdx.y;
  const int n8 = (y < 3) ? n8a : n8b;
  const int i = blockIdx.x * 256 + threadIdx.x;
  if (i >= n8) return;
  const float* s = (y == 0) ? s0 : (y == 1) ? s1 : (y == 2) ? s2
                 : (y == 3) ? s3 : (y == 4) ? s4 : s5;
  bf16* d = (y == 0) ? d0 : (y == 1) ? d1 : (y == 2) ? d2
          : (y == 3) ? d3 : (y == 4) ? d4 : d5;
  const f32x4* sp = (const f32x4*)s;
  const f32x4 a = sp[2 * i], b = sp[2 * i + 1];
  bf16x8 r;
  r[0] = (bf16)a[0]; r[1] = (bf16)a[1]; r[2] = (bf16)a[2]; r[3] = (bf16)a[3];
  r[4] = (bf16)b[0]; r[5] = (bf16)b[1]; r[6] = (bf16)b[2]; r[7] = (bf16)b[3];
  ((bf16x8*)d)[i] = r;
}

// ---------------------------------------------------------------------------
// QKV projection GEMM, one dispatch (z selects Q/K/V): Y = X.W^T + b
// M = nb*1024, N = 1024, K = 1024. m97-style global_load_lds staging,
// 128x128 tile, 4 waves. BK=64 (was 32): halves the per-K-step
// vmcnt(0)+barrier drain count (the known ~20% stall of this structure)
// at the same total bytes/MFMA. LDS 32 KB. Row layout = 64 bf16 = 128 B,
// 8x16B chunks, phys_chunk = log_chunk ^ (row&7) via pre-swizzled global
// source; fragment read chunk = (hh*4+quad) ^ (l15&7). (Identical to attn's
// sKs layout, measured 0 conflicts.)
// (256^2 8-phase LOST here in R1/R2: 1 block/CU + grid tail at N=1024.)
// Operand orientation per z (packed 8B stores both ways):
//   z<2 (Q,K out [bl,h,s,d]): A = W rows, B = X rows -> acc reg axis = d.
//   z==2 (V out TRANSPOSED [bl,h,d,s]): A = X rows, B = W rows -> reg = s.
// ---------------------------------------------------------------------------
__global__ __launch_bounds__(256, 2)
void proj_kernel(const bf16* __restrict__ Xq, const bf16* __restrict__ Xk,
                 const bf16* __restrict__ Xv,
                 const bf16* __restrict__ Wq, const bf16* __restrict__ Wk,
                 const bf16* __restrict__ Wv,
                 const float* __restrict__ Bq, const float* __restrict__ Bk,
                 const float* __restrict__ Bv,
                 bf16* __restrict__ Yq, bf16* __restrict__ Yk,
                 bf16* __restrict__ Yv) {
  const int z = blockIdx.z;
  const bf16*  X  = (z == 0) ? Xq : (z == 1) ? Xk : Xv;
  const bf16*  W  = (z == 0) ? Wq : (z == 1) ? Wk : Wv;
  const float* Bi = (z == 0) ? Bq : (z == 1) ? Bk : Bv;
  bf16*        Y  = (z == 0) ? Yq : (z == 1) ? Yk : Yv;

  const int m0 = blockIdx.x * 128;
  const int n0 = blockIdx.y * 128;

  // 128 rows x 64 k bf16 each (16 KB each)
  __shared__ __attribute__((aligned(16))) bf16 As[128 * 64];
  __shared__ __attribute__((aligned(16))) bf16 Bs[128 * 64];

  const int t    = threadIdx.x;
  const int l    = t & 63;
  const int w    = t >> 6;
  const int l15  = l & 15;
  const int quad = l >> 4;
  const int wm   = w & 1;   // X-row half
  const int wn   = w >> 1;  // W-row half

  f32x4 acc[4][4];
#pragma unroll
  for (int i = 0; i < 4; ++i)
#pragma unroll
    for (int j = 0; j < 4; ++j) acc[i][j] = (f32x4){0.f, 0.f, 0.f, 0.f};

  // staging: 8-row sub-slabs, 8 lanes/row; lane l -> row +(l>>3), phys chunk
  // l&7; global supplies logical chunk (l&7)^(l>>3) (row&7 == l>>3 here).
  const int srow = l >> 3;
  const int gc8  = (l & 7) ^ srow;
  const int rx7  = l15 & 7;

  for (int k0 = 0; k0 < DIN; k0 += 64) {
    __syncthreads();
#pragma unroll
    for (int c = 0; c < 4; ++c) {
      const int slab = w * 32 + c * 8;
      const int r    = slab + srow;
      async16(X + (size_t)(m0 + r) * DIN + k0 + gc8 * 8, As + slab * 64);
      async16(W + (size_t)(n0 + r) * DIN + k0 + gc8 * 8, Bs + slab * 64);
    }
    __syncthreads();  // vmcnt(0) drain before s_barrier

    bf16x8 xf[4][2], wf[4][2];
#pragma unroll
    for (int i = 0; i < 4; ++i) {
      const int xr = wm * 64 + i * 16 + l15;
      const int wr = wn * 64 + i * 16 + l15;
#pragma unroll
      for (int hh = 0; hh < 2; ++hh) {
        const int chs = ((hh * 4 + quad) ^ rx7) * 8;
        xf[i][hh] = *(const bf16x8*)(As + xr * 64 + chs);
        wf[i][hh] = *(const bf16x8*)(Bs + wr * 64 + chs);
      }
    }
    if (z == 2) {
#pragma unroll
      for (int mi = 0; mi < 4; ++mi)
#pragma unroll
        for (int nj = 0; nj < 4; ++nj) {
          acc[mi][nj] = mfma_bf16(xf[mi][0], wf[nj][0], acc[mi][nj]);
          acc[mi][nj] = mfma_bf16(xf[mi][1], wf[nj][1], acc[mi][nj]);
        }
    } else {
#pragma unroll
      for (int mi = 0; mi < 4; ++mi)
#pragma unroll
        for (int nj = 0; nj < 4; ++nj) {
          acc[mi][nj] = mfma_bf16(wf[mi][0], xf[nj][0], acc[mi][nj]);
          acc[mi][nj] = mfma_bf16(wf[mi][1], xf[nj][1], acc[mi][nj]);
        }
    }
  }

  // acc[mi][nj]: reg rows (quad*4+r) <-> A-operand rows, cols (l15) <-> B rows
  if (z == 2) {
    // V: transposed [bl, h, d, s] — r maps to 4 consecutive s -> 8B store
#pragma unroll
    for (int nj = 0; nj < 4; ++nj) {
      const int o    = n0 + wn * 64 + nj * 16 + l15;
      const float bv = Bi[o];
      const int h    = o >> 6;
      const int d    = o & 63;
#pragma unroll
      for (int mi = 0; mi < 4; ++mi) {
        const int m  = m0 + wm * 64 + mi * 16 + quad * 4;
        const int bl = m >> 10;
        const int s  = m & (SEQL - 1);
        bf16x4 pk;
#pragma unroll
        for (int r = 0; r < 4; ++r) pk[r] = (bf16)(acc[mi][nj][r] + bv);
        *(bf16x4*)(Y + ((size_t)(bl * NH + h) * DK + d) * SEQL + s) = pk;
      }
    }
  } else {
    // Q/K: [bl,h,s,d] — r maps to 4 consecutive d -> 8B store
    const float scale = (z == 0) ? QSCALE : 1.0f;
    const int hq = (n0 + wn * 64) >> 6;  // head index, constant per wave
#pragma unroll
    for (int mi = 0; mi < 4; ++mi) {
      const int dbase = mi * 16 + quad * 4;
      const f32x4 bv4 = *(const f32x4*)(Bi + n0 + wn * 64 + dbase);
#pragma unroll
      for (int nj = 0; nj < 4; ++nj) {
        const int m  = m0 + wm * 64 + nj * 16 + l15;
        const int bl = m >> 10;
        const int s  = m & (SEQL - 1);
        bf16x4 pk;
#pragma unroll
        for (int r = 0; r < 4; ++r)
          pk[r] = (bf16)((acc[mi][nj][r] + bv4[r]) * scale);
        *(bf16x4*)(Y + (size_t)(((bl * NH + hq) << 10) | s) * DK + dbase) = pk;
      }
    }
  }
}

// ---------------------------------------------------------------------------
// Attention (r5 structure — measured best, ~67 us): BK=64, block = (local bh,
// 256 q-rows), 4 waves, 64 q/wave (4 groups). KV double-buffered in LDS with
// counted vmcnt: fragments pulled to regs up front, lgkmcnt(0)+barrier frees
// the buffer, tile tt+2 staged into it, compute runs while loads fly;
// vmcnt(4) at tile end (never 0 in steady state). P stride 76 conflict-free.
// Computes S^T = K.Q^T so each lane holds 4 consecutive keys -> packed b64
// P-writes; P is wave-private (intra-wave LDS ordering, no barrier).
// Exact softmax via exp2 (scale folded into Q); denominator via
// MFMA-with-ones on the rounded P (numerator-consistent).
// [r6 32-q/wave occupancy rebuild REGRESSED: VALUBusy 25->58%. r3 no-staging
//  REGRESSED: latency-exposed. Do not revisit either.]
// ---------------------------------------------------------------------------
__global__ __launch_bounds__(256, 2)
void attn_kernel(const bf16* __restrict__ Q, const bf16* __restrict__ K,
                 const bf16* __restrict__ V, float* __restrict__ Out, int b0) {
  const int bhl = blockIdx.x;        // same-bh blocks share K/V (XCD locality)
  const int q0  = blockIdx.y * 256;
  const int bg  = b0 + (bhl >> 4);
  const int h   = bhl & 15;
  const int t    = threadIdx.x;
  const int l    = t & 63;
  const int w    = t >> 6;
  const int l15  = l & 15;
  const int quad = l >> 4;

  const bf16* Qh = Q + (size_t)bhl * SEQL * DK;
  const bf16* Kh = K + (size_t)bhl * SEQL * DK;
  const bf16* Vh = V + (size_t)bhl * DK * SEQL;  // [d][s]

  __shared__ __attribute__((aligned(16))) bf16 sKs[2][64 * 64];      // 16 KB
  __shared__ __attribute__((aligned(16))) bf16 sVt[2][64 * 64];      // 16 KB
  __shared__ __attribute__((aligned(16))) bf16 sPl[4][4][16 * PSTR]; // 38 KB

  // Q fragments (pre-scaled): lane holds Q[q=l15][d=quad*8+j], 2 d-halves
  bf16x8 qf[4][2];
#pragma unroll
  for (int g = 0; g < 4; ++g)
#pragma unroll
    for (int hh = 0; hh < 2; ++hh)
      qf[g][hh] = *(const bf16x8*)(Qh + (size_t)(q0 + w * 64 + g * 16 + l15) * DK +
                                   hh * 32 + quad * 8);

  bf16x8 ones;
#pragma unroll
  for (int j = 0; j < 8; ++j) ones[j] = (bf16)1.0f;

  f32x4 oacc[4][4];
#pragma unroll
  for (int g = 0; g < 4; ++g)
#pragma unroll
    for (int n = 0; n < 4; ++n) oacc[g][n] = (f32x4){0.f, 0.f, 0.f, 0.f};
  f32x4 sacc[4];
#pragma unroll
  for (int g = 0; g < 4; ++g) sacc[g] = (f32x4){0.f, 0.f, 0.f, 0.f};

  const int drow   = l >> 3;  // DMA: row within 8-row sub-slab
  const int dchunk = l & 7;   // DMA: physical 16B chunk

#define STAGE_KV(T, BB)                                                      \
  {                                                                          \
    const int kbs = (T) * 64;                                                \
    _Pragma("unroll")                                                        \
    for (int i = 0; i < 2; ++i) {                                            \
      const int r = w * 16 + i * 8 + drow;                                   \
      async16(Kh + (size_t)(kbs + r) * DK + (dchunk ^ (r & 7)) * 8,          \
              &sKs[BB][(w * 16 + i * 8) * 64]);                              \
      async16(Vh + (size_t)r * SEQL + kbs + (dchunk ^ (r & 7)) * 8,          \
              &sVt[BB][(w * 16 + i * 8) * 64]);                              \
    }                                                                        \
  }

  const int NT = SEQL / 64;  // 16

  // prologue: stage tiles 0 and 1; wait tile 0 (tile 1 stays in flight)
  STAGE_KV(0, 0)
  STAGE_KV(1, 1)
  asm volatile("s_waitcnt vmcnt(4)" ::: "memory");
  __builtin_amdgcn_s_barrier();

  for (int tt = 0; tt < NT; ++tt) {
    const int bb = tt & 1;

    // K fragments: A-operand K[key=c*16+l15][d=hh*32+quad*8+j]
    bf16x8 kf[4][2];
#pragma unroll
    for (int c = 0; c < 4; ++c)
#pragma unroll
      for (int hh = 0; hh < 2; ++hh)
        kf[c][hh] = *(const bf16x8*)(&sKs[bb][(c * 16 + l15) * 64 +
                                     (((hh * 4 + quad) ^ (l15 & 7)) * 8)]);
    // V^T fragments: B-operand V^T[d=n*16+l15][k=hh*32+quad*8+j]
    bf16x8 vfr[4][2];
#pragma unroll
    for (int n = 0; n < 4; ++n)
#pragma unroll
      for (int hh = 0; hh < 2; ++hh)
        vfr[n][hh] = *(const bf16x8*)(&sVt[bb][(n * 16 + l15) * 64 +
                                      (((hh * 4 + quad) ^ (l15 & 7)) * 8)]);

    asm volatile("s_waitcnt lgkmcnt(0)" ::: "memory");
    __builtin_amdgcn_sched_barrier(0);  // rule #18: pin reg-MFMAs below wait
    __builtin_amdgcn_s_barrier();       // all waves hold K/V in regs -> buf free
    if (tt + 2 < NT) STAGE_KV(tt + 2, bb)
    __builtin_amdgcn_sched_barrier(0);

    // S^T = K.Q^T -> exp2 -> packed b64 P-writes (P stored [q][key], str 76)
#pragma unroll
    for (int g = 0; g < 4; ++g) {
#pragma unroll
      for (int c = 0; c < 4; ++c) {
        f32x4 cs = (f32x4){0.f, 0.f, 0.f, 0.f};
        cs = mfma_bf16(kf[c][0], qf[g][0], cs);
        cs = mfma_bf16(kf[c][1], qf[g][1], cs);
        bf16x4 pk;
#pragma unroll
        for (int r = 0; r < 4; ++r) pk[r] = (bf16)exp2f(cs[r]);
        // lane (quad,l15) holds P[q=l15][keys c*16+quad*4 .. +3]
        *(bf16x4*)(&sPl[w][g][l15 * PSTR + c * 16 + quad * 4]) = pk;
      }
    }
    // no barrier: sPl[w] is wave-private; lgkmcnt orders write->read

#pragma unroll
    for (int g = 0; g < 4; ++g) {
      const bf16x8 pf0 = *(const bf16x8*)(&sPl[w][g][l15 * PSTR + quad * 8]);
      const bf16x8 pf1 = *(const bf16x8*)(&sPl[w][g][l15 * PSTR + 32 + quad * 8]);
#pragma unroll
      for (int n = 0; n < 4; ++n) {
        oacc[g][n] = mfma_bf16(pf0, vfr[n][0], oacc[g][n]);
        oacc[g][n] = mfma_bf16(pf1, vfr[n][1], oacc[g][n]);
      }
      sacc[g] = mfma_bf16(pf0, ones, sacc[g]);
      sacc[g] = mfma_bf16(pf1, ones, sacc[g]);
    }

    // counted drain: tile tt+1 landed for all waves; tt+2 stays in flight
    if (tt + 2 < NT) {
      asm volatile("s_waitcnt vmcnt(4)" ::: "memory");
    } else if (tt + 2 == NT) {
      asm volatile("s_waitcnt vmcnt(0)" ::: "memory");
    }
    if (tt + 1 < NT) __builtin_amdgcn_s_barrier();
  }
#undef STAGE_KV

  // epilogue: divide by denominator, write fp32 [b, s, h, d]
#pragma unroll
  for (int g = 0; g < 4; ++g) {
    float linv[4];
#pragma unroll
    for (int r = 0; r < 4; ++r) linv[r] = 1.0f / sacc[g][r];
#pragma unroll
    for (int n = 0; n < 4; ++n) {
      const int d = n * 16 + l15;
#pragma unroll
      for (int r = 0; r < 4; ++r) {
        const int qrow = q0 + w * 64 + g * 16 + quad * 4 + r;
        Out[(size_t)((bg * SEQL + qrow) * NH + h) * DK + d] =
            oacc[g][n][r] * linv[r];
      }
    }
  }
}

extern "C" void kernel_launch(void* const* d_in, const int* in_sizes, int n_in,
                              void* d_out, int out_size, void* d_ws,
                              size_t ws_size, hipStream_t stream) {
  const float* q  = (const float*)d_in[0];
  const float* k  = (const float*)d_in[1];
  const float* v  = (const float*)d_in[2];
  const float* Wq = (const float*)d_in[3];
  const float* bq = (const float*)d_in[4];
  const float* Wk = (const float*)d_in[5];
  const float* bk = (const float*)d_in[6];
  const float* Wv = (const float*)d_in[7];
  const float* bv = (const float*)d_in[8];
  float* out = (float*)d_out;

  // ws layout: [Wq,Wk,Wv bf16: 6MB][Xq,Xk,Xv group][Yq,Yk,Yv group]
  const size_t wElems = (size_t)DIN * DIN;
  const size_t wBytes = 3 * wElems * sizeof(bf16);
  const size_t perBatch = 6 * (size_t)SEQL * DIN * sizeof(bf16);  // 12 MB
  int nbg = (ws_size > wBytes) ? (int)((ws_size - wBytes) / perBatch) : 1;
  if (nbg < 1) nbg = 1;
  if (nbg > NB) nbg = NB;

  bf16* Wqb = (bf16*)d_ws;
  bf16* Wkb = Wqb + wElems;
  bf16* Wvb = Wkb + wElems;
  const size_t g1 = (size_t)nbg * SEQL * DIN;
  bf16* Xqb = Wvb + wElems;
  bf16* Xkb = Xqb + g1;
  bf16* Xvb = Xkb + g1;
  bf16* Yqb = Xvb + g1;
  bf16* Ykb = Yqb + g1;
  bf16* Yvb = Ykb + g1;

  const int w8 = (int)(wElems / 8);

  for (int b0 = 0; b0 < NB; b0 += nbg) {
    const int nb = (NB - b0 < nbg) ? (NB - b0) : nbg;
    const int n8 = nb * SEQL * DIN / 8;
    const size_t xoff = (size_t)b0 * SEQL * DIN;
    const int xb = (n8 + 255) / 256;
    const int wb = (w8 + 255) / 256;
    dim3 gX((xb > wb) ? xb : wb, 6);
    cvt6_kernel<<<gX, 256, 0, stream>>>(q + xoff, k + xoff, v + xoff,
                                        Wq, Wk, Wv,
                                        Xqb, Xkb, Xvb, Wqb, Wkb, Wvb,
                                        n8, w8);

    dim3 gP(nb * 8, 8, 3);
    proj_kernel<<<gP, 256, 0, stream>>>(Xqb, Xkb, Xvb, Wqb, Wkb, Wvb,
                                        bq, bk, bv, Yqb, Ykb, Yvb);

    dim3 gA(nb * NH, SEQL / 256);
    attn_kernel<<<gA, 256, 0, stream>>>(Yqb, Ykb, Yvb, out, b0);
  }
}